// Round 8
// baseline (136.752 us; speedup 1.0000x reference)
//
#include <hip/hip_runtime.h>
#include <math.h>

#define BATCH 8
#define SEQ   4096
#define DM    128
#define DS    128
#define N2    4096   // complex FFT length (r2c half-size; conv length 8192)
#define NT    256
#define NTP   256

__device__ __forceinline__ float2 cmulf(float2 a, float2 b) {
    return make_float2(a.x * b.x - a.y * b.y, a.x * b.y + a.y * b.x);
}
__device__ __forceinline__ float2 caddf(float2 a, float2 b) { return make_float2(a.x + b.x, a.y + b.y); }
__device__ __forceinline__ float2 csubf(float2 a, float2 b) { return make_float2(a.x - b.x, a.y - b.y); }
__device__ __forceinline__ float2 conjf2(float2 a) { return make_float2(a.x, -a.y); }
__device__ __forceinline__ float2 cisf(float t) { float s, c; __sincosf(t, &s, &c); return make_float2(c, s); }

// nibble-reverse of 12-bit index (involution): bin k sits at logical position nibrev(k)
__device__ __forceinline__ int nibrev(int k) { return ((k & 15) << 8) | (k & 0xF0) | (k >> 8); }
// LDS anti-conflict swizzle (involutive bijection)
__device__ __forceinline__ int physi(int a) { return a ^ ((a >> 4) & 15); }

// ---------------- in-register DFT-16 (verified R4) ----------------
__device__ __forceinline__ void dft16_fwd(const float2 x[16], float2 Xh[16]) {
    const float2 W[10] = { {1.f,0.f},
        {0.92387953f,-0.38268343f},{0.70710678f,-0.70710678f},{0.38268343f,-0.92387953f},
        {0.f,-1.f},{-0.38268343f,-0.92387953f},{-0.70710678f,-0.70710678f},
        {-0.92387953f,-0.38268343f},{-1.f,0.f},{-0.92387953f,0.38268343f} };
    float2 y[16];
#pragma unroll
    for (int j = 0; j < 4; ++j) {
        float2 a0 = x[j], a1 = x[j+4], a2 = x[j+8], a3 = x[j+12];
        float2 t0 = caddf(a0,a2), t1 = csubf(a0,a2);
        float2 t2 = caddf(a1,a3), t3 = csubf(a1,a3);
        float2 b1 = make_float2(t1.x + t3.y, t1.y - t3.x);
        float2 b3 = make_float2(t1.x - t3.y, t1.y + t3.x);
        y[j]    = caddf(t0,t2);
        y[j+4]  = cmulf(b1, W[j]);
        y[j+8]  = cmulf(csubf(t0,t2), W[2*j]);
        y[j+12] = cmulf(b3, W[3*j]);
    }
#pragma unroll
    for (int g = 0; g < 4; ++g) {
        float2 a0 = y[4*g], a1 = y[4*g+1], a2 = y[4*g+2], a3 = y[4*g+3];
        float2 t0 = caddf(a0,a2), t1 = csubf(a0,a2);
        float2 t2 = caddf(a1,a3), t3 = csubf(a1,a3);
        Xh[4*g]   = caddf(t0,t2);
        Xh[4*g+1] = make_float2(t1.x + t3.y, t1.y - t3.x);
        Xh[4*g+2] = csubf(t0,t2);
        Xh[4*g+3] = make_float2(t1.x - t3.y, t1.y + t3.x);
    }
}
__device__ __forceinline__ void dft16_inv(const float2 x[16], float2 Xh[16]) {
    const float2 W[10] = { {1.f,0.f},
        {0.92387953f,0.38268343f},{0.70710678f,0.70710678f},{0.38268343f,0.92387953f},
        {0.f,1.f},{-0.38268343f,0.92387953f},{-0.70710678f,0.70710678f},
        {-0.92387953f,0.38268343f},{-1.f,0.f},{-0.92387953f,-0.38268343f} };
    float2 y[16];
#pragma unroll
    for (int j = 0; j < 4; ++j) {
        float2 a0 = x[j], a1 = x[j+4], a2 = x[j+8], a3 = x[j+12];
        float2 t0 = caddf(a0,a2), t1 = csubf(a0,a2);
        float2 t2 = caddf(a1,a3), t3 = csubf(a1,a3);
        float2 b1 = make_float2(t1.x - t3.y, t1.y + t3.x);
        float2 b3 = make_float2(t1.x + t3.y, t1.y - t3.x);
        y[j]    = caddf(t0,t2);
        y[j+4]  = cmulf(b1, W[j]);
        y[j+8]  = cmulf(csubf(t0,t2), W[2*j]);
        y[j+12] = cmulf(b3, W[3*j]);
    }
#pragma unroll
    for (int g = 0; g < 4; ++g) {
        float2 a0 = y[4*g], a1 = y[4*g+1], a2 = y[4*g+2], a3 = y[4*g+3];
        float2 t0 = caddf(a0,a2), t1 = csubf(a0,a2);
        float2 t2 = caddf(a1,a3), t3 = csubf(a1,a3);
        Xh[4*g]   = caddf(t0,t2);
        Xh[4*g+1] = make_float2(t1.x - t3.y, t1.y + t3.x);
        Xh[4*g+2] = csubf(t0,t2);
        Xh[4*g+3] = make_float2(t1.x + t3.y, t1.y - t3.x);
    }
}

// ---------------- single-row radix-16 LDS stages (verified R4; used by fftK_PQ) ----------------

template<int Q>
__device__ __forceinline__ void stage_fwd(float2* z, int t) {
    float2 x[16], Xh[16];
    int adr[16];
    if (Q == 16) {
        int j = t & 15, top = t >> 4;
#pragma unroll
        for (int r = 0; r < 16; ++r) adr[r] = (top << 8) + (r << 4) + (j ^ r);
    } else { // Q == 1
        int j4 = t & 15;
#pragma unroll
        for (int r = 0; r < 16; ++r) adr[r] = (t << 4) + (j4 ^ r);
    }
#pragma unroll
    for (int r = 0; r < 16; ++r) x[r] = z[adr[r]];
    dft16_fwd(x, Xh);
    if (Q > 1) {
        int j = t & (Q - 1);
        float2 w1 = cisf(-(float)M_PI / (8.0f * (float)Q) * (float)j);
        float2 w = make_float2(1.f, 0.f);
#pragma unroll
        for (int k = 0; k < 16; ++k) {
            int sk = ((k & 3) << 2) | (k >> 2);
            z[adr[k]] = cmulf(Xh[sk], w);
            w = cmulf(w, w1);
        }
    } else {
#pragma unroll
        for (int k = 0; k < 16; ++k) {
            int sk = ((k & 3) << 2) | (k >> 2);
            z[adr[k]] = Xh[sk];
        }
    }
}

__device__ __forceinline__ void fwd_first(float2* z, const float2* __restrict__ vrow, int t) {
    float2 x[16], Xh[16];
#pragma unroll
    for (int r = 0; r < 8; ++r) x[r] = vrow[t + (r << 8)];
#pragma unroll
    for (int r = 8; r < 16; ++r) x[r] = make_float2(0.f, 0.f);
    dft16_fwd(x, Xh);
    int b0 = t ^ ((t >> 4) & 15);
    float2 w1 = cisf(-(float)M_PI / 2048.0f * (float)t);
    float2 w = make_float2(1.f, 0.f);
#pragma unroll
    for (int k = 0; k < 16; ++k) {
        int sk = ((k & 3) << 2) | (k >> 2);
        z[b0 + (k << 8)] = cmulf(Xh[sk], w);
        w = cmulf(w, w1);
    }
}

// ---------------- paired (two-sequence) radix-16 stages: twiddles/addresses shared ----------------

template<int Q>
__device__ __forceinline__ void stage_fwd2(float2* z0, float2* z1, int t) {
    float2 x0[16], X0[16], x1[16], X1[16];
    int adr[16];
    if (Q == 16) {
        int j = t & 15, top = t >> 4;
#pragma unroll
        for (int r = 0; r < 16; ++r) adr[r] = (top << 8) + (r << 4) + (j ^ r);
    } else {
        int j4 = t & 15;
#pragma unroll
        for (int r = 0; r < 16; ++r) adr[r] = (t << 4) + (j4 ^ r);
    }
#pragma unroll
    for (int r = 0; r < 16; ++r) { x0[r] = z0[adr[r]]; x1[r] = z1[adr[r]]; }
    dft16_fwd(x0, X0);
    dft16_fwd(x1, X1);
    if (Q > 1) {
        int j = t & (Q - 1);
        float2 w1 = cisf(-(float)M_PI / (8.0f * (float)Q) * (float)j);
        float2 w = make_float2(1.f, 0.f);
#pragma unroll
        for (int k = 0; k < 16; ++k) {
            int sk = ((k & 3) << 2) | (k >> 2);
            z0[adr[k]] = cmulf(X0[sk], w);
            z1[adr[k]] = cmulf(X1[sk], w);
            w = cmulf(w, w1);
        }
    } else {
#pragma unroll
        for (int k = 0; k < 16; ++k) {
            int sk = ((k & 3) << 2) | (k >> 2);
            z0[adr[k]] = X0[sk];
            z1[adr[k]] = X1[sk];
        }
    }
}

template<int Q>
__device__ __forceinline__ void stage_inv2(float2* z0, float2* z1, int t) {
    float2 x0[16], X0[16], x1[16], X1[16];
    int adr[16];
    if (Q == 16) {
        int j = t & 15, top = t >> 4;
#pragma unroll
        for (int r = 0; r < 16; ++r) adr[r] = (top << 8) + (r << 4) + (j ^ r);
    } else {
        int j4 = t & 15;
#pragma unroll
        for (int r = 0; r < 16; ++r) adr[r] = (t << 4) + (j4 ^ r);
    }
    if (Q > 1) {
        int j = t & (Q - 1);
        float2 w1 = cisf((float)M_PI / (8.0f * (float)Q) * (float)j);
        float2 w = make_float2(1.f, 0.f);
#pragma unroll
        for (int k = 0; k < 16; ++k) {
            x0[k] = cmulf(z0[adr[k]], w);
            x1[k] = cmulf(z1[adr[k]], w);
            w = cmulf(w, w1);
        }
    } else {
#pragma unroll
        for (int k = 0; k < 16; ++k) { x0[k] = z0[adr[k]]; x1[k] = z1[adr[k]]; }
    }
    dft16_inv(x0, X0);
    dft16_inv(x1, X1);
#pragma unroll
    for (int r = 0; r < 16; ++r) {
        int sr = ((r & 3) << 2) | (r >> 2);
        z0[adr[r]] = X0[sr];
        z1[adr[r]] = X1[sr];
    }
}

__device__ __forceinline__ void fwd_first2(float2* z0, float2* z1,
                                           const float2* __restrict__ v0,
                                           const float2* __restrict__ v1, int t) {
    float2 x0[16], X0[16], x1[16], X1[16];
#pragma unroll
    for (int r = 0; r < 8; ++r) { x0[r] = v0[t + (r << 8)]; x1[r] = v1[t + (r << 8)]; }
#pragma unroll
    for (int r = 8; r < 16; ++r) { x0[r] = make_float2(0.f,0.f); x1[r] = make_float2(0.f,0.f); }
    dft16_fwd(x0, X0);
    dft16_fwd(x1, X1);
    int b0 = t ^ ((t >> 4) & 15);
    float2 w1 = cisf(-(float)M_PI / 2048.0f * (float)t);
    float2 w = make_float2(1.f, 0.f);
#pragma unroll
    for (int k = 0; k < 16; ++k) {
        int sk = ((k & 3) << 2) | (k >> 2);
        z0[b0 + (k << 8)] = cmulf(X0[sk], w);
        z1[b0 + (k << 8)] = cmulf(X1[sk], w);
        w = cmulf(w, w1);
    }
}

__device__ __forceinline__ void inv_last_store2(const float2* z0, const float2* z1,
                                                float2* __restrict__ v0, float2* __restrict__ v1,
                                                int t, float dv) {
    float2 x0[16], X0[16], x1[16], X1[16];
    int b0 = t ^ ((t >> 4) & 15);
    float2 w1 = cisf((float)M_PI / 2048.0f * (float)t);
    float2 w = make_float2(1.f, 0.f);
#pragma unroll
    for (int k = 0; k < 16; ++k) {
        x0[k] = cmulf(z0[b0 + (k << 8)], w);
        x1[k] = cmulf(z1[b0 + (k << 8)], w);
        w = cmulf(w, w1);
    }
    dft16_inv(x0, X0);
    dft16_inv(x1, X1);
    const float invN = 1.0f / 4096.0f;
#pragma unroll
    for (int r = 0; r < 8; ++r) {
        int sr = ((r & 3) << 2) | (r >> 2);
        float2 xv0 = v0[t + (r << 8)];
        float2 xv1 = v1[t + (r << 8)];
        v0[t + (r << 8)] = make_float2(X0[sr].x * invN + dv * xv0.x, X0[sr].y * invN + dv * xv0.y);
        v1[t + (r << 8)] = make_float2(X1[sr].x * invN + dv * xv1.x, X1[sr].y * invN + dv * xv1.y);
    }
}

// ---------------- P/Q pair coefficients (validated R3/R4; verbatim) ----------------
__device__ __forceinline__ void pq_one(float2 Kk, float2 Kkp, float thk,
                                       float2 fap, float2 fbp,
                                       float2* P, float2* Q) {
    float2 e  = cisf(-thk);
    float2 fa = make_float2(0.5f * (1.f + e.y), -0.5f * e.x);
    float2 fb = make_float2(0.5f * (1.f - e.y),  0.5f * e.x);
    float2 ak = cmulf(Kk, fa), bk = cmulf(Kk, fb);
    float2 apv = cmulf(Kkp, fap), bpv = cmulf(Kkp, fbp);
    float2 g = make_float2(0.5f * (1.f + e.y), 0.5f * e.x);
    float2 h = make_float2(0.5f * (1.f - e.y), -0.5f * e.x);
    *P = caddf(cmulf(g, ak), cmulf(h, conjf2(bpv)));
    *Q = caddf(cmulf(g, bk), cmulf(h, conjf2(apv)));
}
__device__ __forceinline__ void pq_pair(float2 Kk, float2 Kkp, float thk, float thkp,
                                        float2* Pk, float2* Qk, float2* Pkp, float2* Qkp) {
    float2 e  = cisf(-thk);
    float2 ep = cisf(-thkp);
    float2 fa  = make_float2(0.5f * (1.f + e.y),  -0.5f * e.x);
    float2 fb  = make_float2(0.5f * (1.f - e.y),   0.5f * e.x);
    float2 fap = make_float2(0.5f * (1.f + ep.y), -0.5f * ep.x);
    float2 fbp = make_float2(0.5f * (1.f - ep.y),  0.5f * ep.x);
    pq_one(Kk,  Kkp, thk,  fap, fbp, Pk,  Qk);
    pq_one(Kkp, Kk,  thkp, fa,  fb,  Pkp, Qkp);
}

// ---------------- prep kernels (R7 verbatim) ----------------

__global__ void prep_G(const float* __restrict__ Cm, const float* __restrict__ Bm,
                       float* __restrict__ GT) {
    int gid = blockIdx.x * blockDim.x + threadIdx.x;
    int m = gid >> 7, j = gid & 127;
    float acc = 0.f;
    for (int i = 0; i < DS; ++i) acc += Cm[m * DS + i] * Bm[i * DM + j];
    GT[j * DM + m] = acc;
}

__global__ void prep_psum2(const float* __restrict__ Lam, const float* __restrict__ logdt,
                           float* __restrict__ Psum) {
    __shared__ float E[DM];
    int s = blockIdx.x >> 1, half = blockIdx.x & 1;
    int t = threadIdx.x;
    if (t < DM) E[t] = __expf(logdt[t]) * Lam[s];
    __syncthreads();
    int l0 = t + 2048 * half;
    float acc[8] = {0.f,0.f,0.f,0.f,0.f,0.f,0.f,0.f};
    for (int m = 0; m < DM; ++m) {
        float e = E[m];
        float w = __expf(e * (float)l0);
        float r = __expf(e * 256.0f);
#pragma unroll
        for (int i = 0; i < 8; ++i) { acc[i] += w; w *= r; }
    }
#pragma unroll
    for (int i = 0; i < 8; ++i) Psum[s * SEQ + l0 + 256 * i] = acc[i];
}

__global__ void prep_K2(const float* __restrict__ GT, const float* __restrict__ Psum,
                        float* __restrict__ K) {
    __shared__ float4 PT[DS][4];
    int l0 = blockIdx.x * 16;
    int t = threadIdx.x;
    for (int idx = t; idx < 512; idx += NTP) {
        int s = idx >> 2, q = idx & 3;
        PT[s][q] = ((const float4*)(Psum + s * SEQ + l0))[q];
    }
    __syncthreads();
    int m = t & 127, half = t >> 7;
    float acc[8] = {0.f,0.f,0.f,0.f,0.f,0.f,0.f,0.f};
    for (int s = 0; s < DS; ++s) {
        float g = GT[s * DM + m];
        float4 p0 = PT[s][half * 2], p1 = PT[s][half * 2 + 1];
        acc[0] += g * p0.x; acc[1] += g * p0.y; acc[2] += g * p0.z; acc[3] += g * p0.w;
        acc[4] += g * p1.x; acc[5] += g * p1.y; acc[6] += g * p1.z; acc[7] += g * p1.w;
    }
    float4* kp = (float4*)(K + (size_t)m * SEQ + l0 + half * 8);
    kp[0] = make_float4(acc[0], acc[1], acc[2], acc[3]);
    kp[1] = make_float4(acc[4], acc[5], acc[6], acc[7]);
}

// ---------------- fftK_PQ (R7 verbatim) ----------------
__global__ void __launch_bounds__(NT, 4) fftK_PQ(const float* __restrict__ K,
                                                 float4* __restrict__ PQ) {
    __shared__ __align__(16) float2 z[N2];
    int t = threadIdx.x, m = blockIdx.x;
    const float2* krow = (const float2*)(K + (size_t)m * SEQ);

    fwd_first(z, krow, t);  __syncthreads();
    stage_fwd<16>(z, t);    __syncthreads();
    stage_fwd<1>(z, t);     __syncthreads();

    float4* dst = PQ + (size_t)m * 4096;
#pragma unroll
    for (int c = 0; c < 8; ++c) {
        int idx2 = (((c << 8) | t)) << 1;
        int pos = (t << 4) | c;
        float2 Pk, Qk, Pkp, Qkp;
        if (pos == 0) {
            float2 v0 = z[0];
            float2 v2 = z[8];
            float2 Ku0    = make_float2(v0.x + v0.y, 0.f);
            float2 Ku4096 = make_float2(v0.x - v0.y, 0.f);
            float2 Ku2048 = conjf2(v2);
            float2 Pd, Qd;
            pq_pair(Ku0, Ku4096, 0.f, (float)M_PI, &Pk, &Qk, &Pd, &Qd);
            float th2 = 0.5f * (float)M_PI;
            pq_pair(Ku2048, Ku2048, th2, th2, &Pkp, &Qkp, &Pd, &Qd);
        } else {
            int k  = nibrev(pos);
            int kp = 4096 - k;
            float2 va = z[physi(pos)];
            float2 vb = z[physi(nibrev(kp))];
            float thk  = (float)M_PI * (float)k / 4096.0f;
            float thkp = (float)M_PI - thk;
            float2 e  = cisf(-thk);
            float2 cb = conjf2(vb);
            float2 s  = caddf(va, cb), d = csubf(va, cb);
            float2 pr = cmulf(e, d);
            float2 Kuk = make_float2(0.5f * (s.x + pr.y), 0.5f * (s.y - pr.x));
            float2 ep = make_float2(-e.x, e.y);
            float2 ca = conjf2(va);
            float2 s2 = caddf(vb, ca), d2 = csubf(vb, ca);
            float2 p2 = cmulf(ep, d2);
            float2 Kukp = make_float2(0.5f * (s2.x + p2.y), 0.5f * (s2.y - p2.x));
            pq_pair(Kuk, Kukp, thk, thkp, &Pk, &Qk, &Pkp, &Qkp);
        }
        dst[idx2]     = make_float4(Pk.x, Pk.y, Qk.x, Qk.y);
        dst[idx2 + 1] = make_float4(Pkp.x, Pkp.y, Qkp.x, Qkp.y);
    }
}

// ---------------- main convolution: TWO sequences per block (shared twiddles/PQ) ----------------
__global__ void __launch_bounds__(NT, 2) conv2(float* __restrict__ xt,
                                               const float4* __restrict__ PQ,
                                               const float* __restrict__ Dv) {
    __shared__ __align__(16) float2 z0[N2];
    __shared__ __align__(16) float2 z1[N2];
    int t = threadIdx.x;
    int m  = blockIdx.x & (DM - 1);
    int pr = blockIdx.x >> 7;            // 0..3: batch pair
    float2* xrow0 = (float2*)(xt + (((size_t)(2 * pr) * DM + m) << 12));
    float2* xrow1 = (float2*)(xt + (((size_t)(2 * pr + 1) * DM + m) << 12));

    fwd_first2(z0, z1, xrow0, xrow1, t);  __syncthreads();
    stage_fwd2<16>(z0, z1, t);            __syncthreads();
    stage_fwd2<1>(z0, z1, t);             __syncthreads();

    // pointwise: W = P*V + Q*conj(V[partner]); one thread per pair; PQ read once for both rows
    {
        const float4* pq = PQ + (size_t)m * 4096;
#pragma unroll
        for (int c = 0; c < 8; ++c) {
            int idx2 = (((c << 8) | t)) << 1;
            int pos = (t << 4) | c;
            float4 lo = pq[idx2];
            float4 hi = pq[idx2 + 1];
            float2 Plo = make_float2(lo.x, lo.y), Qlo = make_float2(lo.z, lo.w);
            float2 Phi = make_float2(hi.x, hi.y), Qhi = make_float2(hi.z, hi.w);
            if (pos == 0) {
                float2 a0 = z0[0], a1 = z1[0];
                z0[0] = caddf(cmulf(Plo, a0), cmulf(Qlo, conjf2(a0)));
                z1[0] = caddf(cmulf(Plo, a1), cmulf(Qlo, conjf2(a1)));
                float2 b0 = z0[8], b1 = z1[8];
                z0[8] = caddf(cmulf(Phi, b0), cmulf(Qhi, conjf2(b0)));
                z1[8] = caddf(cmulf(Phi, b1), cmulf(Qhi, conjf2(b1)));
            } else {
                int k  = nibrev(pos);
                int i  = physi(pos);
                int ip = physi(nibrev(4096 - k));
                float2 va0 = z0[i], vb0 = z0[ip];
                float2 va1 = z1[i], vb1 = z1[ip];
                z0[i]  = caddf(cmulf(Plo, va0), cmulf(Qlo, conjf2(vb0)));
                z0[ip] = caddf(cmulf(Phi, vb0), cmulf(Qhi, conjf2(va0)));
                z1[i]  = caddf(cmulf(Plo, va1), cmulf(Qlo, conjf2(vb1)));
                z1[ip] = caddf(cmulf(Phi, vb1), cmulf(Qhi, conjf2(va1)));
            }
        }
    }
    __syncthreads();

    stage_inv2<1>(z0, z1, t);             __syncthreads();
    stage_inv2<16>(z0, z1, t);            __syncthreads();
    inv_last_store2(z0, z1, xrow0, xrow1, t, Dv[m]);
}

// ---------------- float4 transposes (R7 verbatim) ----------------
__global__ void transpose_xin(const float* __restrict__ x, float* __restrict__ xt) {
    __shared__ float tile[32][33];
    int b = blockIdx.z;
    int l0 = blockIdx.x * 32, m0 = blockIdx.y * 32;
    int t = threadIdx.x;
    int lr = t >> 3, mc4 = (t & 7) * 4;
    float4 v = *(const float4*)&x[(size_t)b * SEQ * DM + (size_t)(l0 + lr) * DM + m0 + mc4];
    tile[lr][mc4 + 0] = v.x; tile[lr][mc4 + 1] = v.y;
    tile[lr][mc4 + 2] = v.z; tile[lr][mc4 + 3] = v.w;
    __syncthreads();
    int mr = t >> 3, lc4 = (t & 7) * 4;
    float4 o = make_float4(tile[lc4 + 0][mr], tile[lc4 + 1][mr],
                           tile[lc4 + 2][mr], tile[lc4 + 3][mr]);
    *(float4*)&xt[(size_t)b * DM * SEQ + (size_t)(m0 + mr) * SEQ + l0 + lc4] = o;
}

__global__ void transpose_yout(const float* __restrict__ yt, float* __restrict__ out) {
    __shared__ float tile[32][33];
    int b = blockIdx.z;
    int l0 = blockIdx.x * 32, m0 = blockIdx.y * 32;
    int t = threadIdx.x;
    int mr = t >> 3, lc4 = (t & 7) * 4;
    float4 v = *(const float4*)&yt[(size_t)b * DM * SEQ + (size_t)(m0 + mr) * SEQ + l0 + lc4];
    tile[mr][lc4 + 0] = v.x; tile[mr][lc4 + 1] = v.y;
    tile[mr][lc4 + 2] = v.z; tile[mr][lc4 + 3] = v.w;
    __syncthreads();
    int lr = t >> 3, mc4 = (t & 7) * 4;
    float4 o = make_float4(tile[mc4 + 0][lr], tile[mc4 + 1][lr],
                           tile[mc4 + 2][lr], tile[mc4 + 3][lr]);
    *(float4*)&out[(size_t)b * SEQ * DM + (size_t)(l0 + lr) * DM + m0 + mc4] = o;
}

extern "C" void kernel_launch(void* const* d_in, const int* in_sizes, int n_in,
                              void* d_out, int out_size, void* d_ws, size_t ws_size,
                              hipStream_t stream) {
    const float* x     = (const float*)d_in[0];
    const float* Lam   = (const float*)d_in[1];
    const float* Bm    = (const float*)d_in[2];
    const float* Cm    = (const float*)d_in[3];
    const float* Dv    = (const float*)d_in[4];
    const float* logdt = (const float*)d_in[5];
    float* out = (float*)d_out;

    float*  ws   = (float*)d_ws;
    float*  xt   = ws;                                   // 4,194,304 floats (16 MB)
    float4* PQ   = (float4*)(ws + 4194304);              // 128*2048*2 float4 (8 MB)
    float*  K    = ws + 4194304 + 2097152;               // 524,288 floats (2 MB)
    float*  Psum = K + 524288;                           // 524,288 floats (2 MB)
    float*  GT   = Psum + 524288;                        // 16,384 floats

    hipLaunchKernelGGL(prep_G,         dim3(64),         dim3(NTP),  0, stream, Cm, Bm, GT);
    hipLaunchKernelGGL(prep_psum2,     dim3(256),        dim3(NTP),  0, stream, Lam, logdt, Psum);
    hipLaunchKernelGGL(prep_K2,        dim3(256),        dim3(NTP),  0, stream, GT, Psum, K);
    hipLaunchKernelGGL(fftK_PQ,        dim3(128),        dim3(NT),   0, stream, K, PQ);
    hipLaunchKernelGGL(transpose_xin,  dim3(128, 4, 8),  dim3(NT),   0, stream, x, xt);
    hipLaunchKernelGGL(conv2,          dim3(512),        dim3(NT),   0, stream, xt, PQ, Dv);
    hipLaunchKernelGGL(transpose_yout, dim3(128, 4, 8),  dim3(NT),   0, stream, xt, out);
}

// Round 9
// 131.728 us; speedup vs baseline: 1.0381x; 1.0381x over previous
//
#include <hip/hip_runtime.h>
#include <math.h>

#define BATCH 8
#define SEQ   4096
#define DM    128
#define DS    128
#define N2    4096   // complex FFT length (r2c half-size; conv length 8192)
#define NT    256
#define NTP   256

__device__ __forceinline__ float2 cmulf(float2 a, float2 b) {
    return make_float2(a.x * b.x - a.y * b.y, a.x * b.y + a.y * b.x);
}
__device__ __forceinline__ float2 caddf(float2 a, float2 b) { return make_float2(a.x + b.x, a.y + b.y); }
__device__ __forceinline__ float2 csubf(float2 a, float2 b) { return make_float2(a.x - b.x, a.y - b.y); }
__device__ __forceinline__ float2 conjf2(float2 a) { return make_float2(a.x, -a.y); }
__device__ __forceinline__ float2 cisf(float t) { float s, c; __sincosf(t, &s, &c); return make_float2(c, s); }

// nibble-reverse of 12-bit index (involution): bin k sits at logical position nibrev(k)
__device__ __forceinline__ int nibrev(int k) { return ((k & 15) << 8) | (k & 0xF0) | (k >> 8); }
// LDS anti-conflict swizzle (involutive bijection)
__device__ __forceinline__ int physi(int a) { return a ^ ((a >> 4) & 15); }
// PQ table slot for logical position pos (transposed so conv reads coalesced)
__device__ __forceinline__ int pqslot(int p) { return ((p & 15) << 8) | (p >> 4); }

// ---------------- in-register DFT-16 (verified R4) ----------------
__device__ __forceinline__ void dft16_fwd(const float2 x[16], float2 Xh[16]) {
    const float2 W[10] = { {1.f,0.f},
        {0.92387953f,-0.38268343f},{0.70710678f,-0.70710678f},{0.38268343f,-0.92387953f},
        {0.f,-1.f},{-0.38268343f,-0.92387953f},{-0.70710678f,-0.70710678f},
        {-0.92387953f,-0.38268343f},{-1.f,0.f},{-0.92387953f,0.38268343f} };
    float2 y[16];
#pragma unroll
    for (int j = 0; j < 4; ++j) {
        float2 a0 = x[j], a1 = x[j+4], a2 = x[j+8], a3 = x[j+12];
        float2 t0 = caddf(a0,a2), t1 = csubf(a0,a2);
        float2 t2 = caddf(a1,a3), t3 = csubf(a1,a3);
        float2 b1 = make_float2(t1.x + t3.y, t1.y - t3.x);
        float2 b3 = make_float2(t1.x - t3.y, t1.y + t3.x);
        y[j]    = caddf(t0,t2);
        y[j+4]  = cmulf(b1, W[j]);
        y[j+8]  = cmulf(csubf(t0,t2), W[2*j]);
        y[j+12] = cmulf(b3, W[3*j]);
    }
#pragma unroll
    for (int g = 0; g < 4; ++g) {
        float2 a0 = y[4*g], a1 = y[4*g+1], a2 = y[4*g+2], a3 = y[4*g+3];
        float2 t0 = caddf(a0,a2), t1 = csubf(a0,a2);
        float2 t2 = caddf(a1,a3), t3 = csubf(a1,a3);
        Xh[4*g]   = caddf(t0,t2);
        Xh[4*g+1] = make_float2(t1.x + t3.y, t1.y - t3.x);
        Xh[4*g+2] = csubf(t0,t2);
        Xh[4*g+3] = make_float2(t1.x - t3.y, t1.y + t3.x);
    }
}
__device__ __forceinline__ void dft16_inv(const float2 x[16], float2 Xh[16]) {
    const float2 W[10] = { {1.f,0.f},
        {0.92387953f,0.38268343f},{0.70710678f,0.70710678f},{0.38268343f,0.92387953f},
        {0.f,1.f},{-0.38268343f,0.92387953f},{-0.70710678f,0.70710678f},
        {-0.92387953f,0.38268343f},{-1.f,0.f},{-0.92387953f,-0.38268343f} };
    float2 y[16];
#pragma unroll
    for (int j = 0; j < 4; ++j) {
        float2 a0 = x[j], a1 = x[j+4], a2 = x[j+8], a3 = x[j+12];
        float2 t0 = caddf(a0,a2), t1 = csubf(a0,a2);
        float2 t2 = caddf(a1,a3), t3 = csubf(a1,a3);
        float2 b1 = make_float2(t1.x - t3.y, t1.y + t3.x);
        float2 b3 = make_float2(t1.x + t3.y, t1.y - t3.x);
        y[j]    = caddf(t0,t2);
        y[j+4]  = cmulf(b1, W[j]);
        y[j+8]  = cmulf(csubf(t0,t2), W[2*j]);
        y[j+12] = cmulf(b3, W[3*j]);
    }
#pragma unroll
    for (int g = 0; g < 4; ++g) {
        float2 a0 = y[4*g], a1 = y[4*g+1], a2 = y[4*g+2], a3 = y[4*g+3];
        float2 t0 = caddf(a0,a2), t1 = csubf(a0,a2);
        float2 t2 = caddf(a1,a3), t3 = csubf(a1,a3);
        Xh[4*g]   = caddf(t0,t2);
        Xh[4*g+1] = make_float2(t1.x - t3.y, t1.y + t3.x);
        Xh[4*g+2] = csubf(t0,t2);
        Xh[4*g+3] = make_float2(t1.x + t3.y, t1.y - t3.x);
    }
}

// ---------------- radix-16 LDS stages (verified R4) ----------------

template<int Q>
__device__ __forceinline__ void stage_fwd(float2* z, int t) {
    float2 x[16], Xh[16];
    int adr[16];
    if (Q == 16) {
        int j = t & 15, top = t >> 4;
#pragma unroll
        for (int r = 0; r < 16; ++r) adr[r] = (top << 8) + (r << 4) + (j ^ r);
    } else { // Q == 1
        int j4 = t & 15;
#pragma unroll
        for (int r = 0; r < 16; ++r) adr[r] = (t << 4) + (j4 ^ r);
    }
#pragma unroll
    for (int r = 0; r < 16; ++r) x[r] = z[adr[r]];
    dft16_fwd(x, Xh);
    if (Q > 1) {
        int j = t & (Q - 1);
        float2 w1 = cisf(-(float)M_PI / (8.0f * (float)Q) * (float)j);
        float2 w = make_float2(1.f, 0.f);
#pragma unroll
        for (int k = 0; k < 16; ++k) {
            int sk = ((k & 3) << 2) | (k >> 2);
            z[adr[k]] = cmulf(Xh[sk], w);
            w = cmulf(w, w1);
        }
    } else {
#pragma unroll
        for (int k = 0; k < 16; ++k) {
            int sk = ((k & 3) << 2) | (k >> 2);
            z[adr[k]] = Xh[sk];
        }
    }
}

template<int Q>
__device__ __forceinline__ void stage_inv(float2* z, int t) {
    float2 x[16], Xh[16];
    int adr[16];
    if (Q == 16) {
        int j = t & 15, top = t >> 4;
#pragma unroll
        for (int r = 0; r < 16; ++r) adr[r] = (top << 8) + (r << 4) + (j ^ r);
    } else {
        int j4 = t & 15;
#pragma unroll
        for (int r = 0; r < 16; ++r) adr[r] = (t << 4) + (j4 ^ r);
    }
    if (Q > 1) {
        int j = t & (Q - 1);
        float2 w1 = cisf((float)M_PI / (8.0f * (float)Q) * (float)j);
        float2 w = make_float2(1.f, 0.f);
#pragma unroll
        for (int k = 0; k < 16; ++k) {
            x[k] = cmulf(z[adr[k]], w);
            w = cmulf(w, w1);
        }
    } else {
#pragma unroll
        for (int k = 0; k < 16; ++k) x[k] = z[adr[k]];
    }
    dft16_inv(x, Xh);
#pragma unroll
    for (int r = 0; r < 16; ++r) {
        int sr = ((r & 3) << 2) | (r >> 2);
        z[adr[r]] = Xh[sr];
    }
}

__device__ __forceinline__ void fwd_first(float2* z, const float2* __restrict__ vrow, int t) {
    float2 x[16], Xh[16];
#pragma unroll
    for (int r = 0; r < 8; ++r) x[r] = vrow[t + (r << 8)];
#pragma unroll
    for (int r = 8; r < 16; ++r) x[r] = make_float2(0.f, 0.f);
    dft16_fwd(x, Xh);
    int b0 = t ^ ((t >> 4) & 15);
    float2 w1 = cisf(-(float)M_PI / 2048.0f * (float)t);
    float2 w = make_float2(1.f, 0.f);
#pragma unroll
    for (int k = 0; k < 16; ++k) {
        int sk = ((k & 3) << 2) | (k >> 2);
        z[b0 + (k << 8)] = cmulf(Xh[sk], w);
        w = cmulf(w, w1);
    }
}

__device__ __forceinline__ void inv_last_store(const float2* z, float2* __restrict__ xrow,
                                               int t, float dv) {
    float2 x[16], Xh[16];
    int b0 = t ^ ((t >> 4) & 15);
    float2 w1 = cisf((float)M_PI / 2048.0f * (float)t);
    float2 w = make_float2(1.f, 0.f);
#pragma unroll
    for (int k = 0; k < 16; ++k) {
        x[k] = cmulf(z[b0 + (k << 8)], w);
        w = cmulf(w, w1);
    }
    dft16_inv(x, Xh);
    const float invN = 1.0f / 4096.0f;
#pragma unroll
    for (int r = 0; r < 8; ++r) {
        int sr = ((r & 3) << 2) | (r >> 2);
        float2 res = Xh[sr];
        float2 xv = xrow[t + (r << 8)];
        xrow[t + (r << 8)] = make_float2(res.x * invN + dv * xv.x, res.y * invN + dv * xv.y);
    }
}

// ---------------- P/Q pair coefficients (validated R3/R4; verbatim) ----------------
__device__ __forceinline__ void pq_one(float2 Kk, float2 Kkp, float thk,
                                       float2 fap, float2 fbp,
                                       float2* P, float2* Q) {
    float2 e  = cisf(-thk);
    float2 fa = make_float2(0.5f * (1.f + e.y), -0.5f * e.x);
    float2 fb = make_float2(0.5f * (1.f - e.y),  0.5f * e.x);
    float2 ak = cmulf(Kk, fa), bk = cmulf(Kk, fb);
    float2 apv = cmulf(Kkp, fap), bpv = cmulf(Kkp, fbp);
    float2 g = make_float2(0.5f * (1.f + e.y), 0.5f * e.x);
    float2 h = make_float2(0.5f * (1.f - e.y), -0.5f * e.x);
    *P = caddf(cmulf(g, ak), cmulf(h, conjf2(bpv)));
    *Q = caddf(cmulf(g, bk), cmulf(h, conjf2(apv)));
}
__device__ __forceinline__ void pq_pair(float2 Kk, float2 Kkp, float thk, float thkp,
                                        float2* Pk, float2* Qk, float2* Pkp, float2* Qkp) {
    float2 e  = cisf(-thk);
    float2 ep = cisf(-thkp);
    float2 fa  = make_float2(0.5f * (1.f + e.y),  -0.5f * e.x);
    float2 fb  = make_float2(0.5f * (1.f - e.y),   0.5f * e.x);
    float2 fap = make_float2(0.5f * (1.f + ep.y), -0.5f * ep.x);
    float2 fbp = make_float2(0.5f * (1.f - ep.y),  0.5f * ep.x);
    pq_one(Kk,  Kkp, thk,  fap, fbp, Pk,  Qk);
    pq_one(Kkp, Kk,  thkp, fa,  fb,  Pkp, Qkp);
}

// ---------------- prep: psum (blocks 0..255) || G (blocks 256..319) ----------------
__global__ void __launch_bounds__(NTP) prep_GP(
    const float* __restrict__ Lam, const float* __restrict__ logdt, float* __restrict__ Psum,
    const float* __restrict__ Cm, const float* __restrict__ Bm, float* __restrict__ GT) {
    int bid = blockIdx.x, t = threadIdx.x;
    if (bid < 256) {
        __shared__ float E[DM];
        int s = bid >> 1, half = bid & 1;
        if (t < DM) E[t] = __expf(logdt[t]) * Lam[s];
        __syncthreads();
        int l0 = t + 2048 * half;
        float acc[8] = {0.f,0.f,0.f,0.f,0.f,0.f,0.f,0.f};
        for (int m = 0; m < DM; ++m) {
            float e = E[m];
            float w = __expf(e * (float)l0);
            float r = __expf(e * 256.0f);
#pragma unroll
            for (int i = 0; i < 8; ++i) { acc[i] += w; w *= r; }
        }
#pragma unroll
        for (int i = 0; i < 8; ++i) Psum[s * SEQ + l0 + 256 * i] = acc[i];
    } else {
        int gid = (bid - 256) * NTP + t;
        int m = gid >> 7, j = gid & 127;
        float acc = 0.f;
        for (int i = 0; i < DS; ++i) acc += Cm[m * DS + i] * Bm[i * DM + j];
        GT[j * DM + m] = acc;   // transposed for prep_K2
    }
}

// K[m,l] = sum_s GT[s,m]*Psum[s,l] (verified R4)
__global__ void prep_K2(const float* __restrict__ GT, const float* __restrict__ Psum,
                        float* __restrict__ K) {
    __shared__ float4 PT[DS][4];
    int l0 = blockIdx.x * 16;
    int t = threadIdx.x;
    for (int idx = t; idx < 512; idx += NTP) {
        int s = idx >> 2, q = idx & 3;
        PT[s][q] = ((const float4*)(Psum + s * SEQ + l0))[q];
    }
    __syncthreads();
    int m = t & 127, half = t >> 7;
    float acc[8] = {0.f,0.f,0.f,0.f,0.f,0.f,0.f,0.f};
    for (int s = 0; s < DS; ++s) {
        float g = GT[s * DM + m];
        float4 p0 = PT[s][half * 2], p1 = PT[s][half * 2 + 1];
        acc[0] += g * p0.x; acc[1] += g * p0.y; acc[2] += g * p0.z; acc[3] += g * p0.w;
        acc[4] += g * p1.x; acc[5] += g * p1.y; acc[6] += g * p1.z; acc[7] += g * p1.w;
    }
    float4* kp = (float4*)(K + (size_t)m * SEQ + l0 + half * 8);
    kp[0] = make_float4(acc[0], acc[1], acc[2], acc[3]);
    kp[1] = make_float4(acc[4], acc[5], acc[6], acc[7]);
}

// ---------------- fftK_PQ: per-POSITION coefficient table ----------------
// PQ[pqslot(pos)] = (P_pos, Q_pos) s.t. W[pos] = P*V[pos] + Q*conj(V[partner(pos)]),
// partner(pos) = nibrev((4096 - nibrev(pos)) & 4095)  (self for pos 0 and 8).
__global__ void __launch_bounds__(NT, 4) fftK_PQ(const float* __restrict__ K,
                                                 float4* __restrict__ PQ) {
    __shared__ __align__(16) float2 z[N2];
    int t = threadIdx.x, m = blockIdx.x;
    const float2* krow = (const float2*)(K + (size_t)m * SEQ);

    fwd_first(z, krow, t);  __syncthreads();
    stage_fwd<16>(z, t);    __syncthreads();
    stage_fwd<1>(z, t);     __syncthreads();

    float4* dst = PQ + (size_t)m * 4096;
#pragma unroll
    for (int c = 0; c < 8; ++c) {
        int pos = (t << 4) | c;            // bit3==0 half: one thread per pair
        float2 Pk, Qk, Pkp, Qkp;
        if (pos == 0) {
            float2 v0 = z[0];
            float2 v2 = z[8];
            float2 Ku0    = make_float2(v0.x + v0.y, 0.f);
            float2 Ku4096 = make_float2(v0.x - v0.y, 0.f);
            float2 Ku2048 = conjf2(v2);
            float2 Pd, Qd;
            pq_pair(Ku0, Ku4096, 0.f, (float)M_PI, &Pk, &Qk, &Pd, &Qd);
            float th2 = 0.5f * (float)M_PI;
            pq_pair(Ku2048, Ku2048, th2, th2, &Pkp, &Qkp, &Pd, &Qd);
            dst[pqslot(0)] = make_float4(Pk.x, Pk.y, Qk.x, Qk.y);     // pos 0 (self-pair)
            dst[pqslot(8)] = make_float4(Pkp.x, Pkp.y, Qkp.x, Qkp.y); // pos 8 (self-pair)
        } else {
            int k  = nibrev(pos);
            int kp = 4096 - k;
            int ppos = nibrev(kp);
            float2 va = z[physi(pos)];
            float2 vb = z[physi(ppos)];
            float thk  = (float)M_PI * (float)k / 4096.0f;
            float thkp = (float)M_PI - thk;
            float2 e  = cisf(-thk);
            float2 cb = conjf2(vb);
            float2 s  = caddf(va, cb), d = csubf(va, cb);
            float2 pr = cmulf(e, d);
            float2 Kuk = make_float2(0.5f * (s.x + pr.y), 0.5f * (s.y - pr.x));
            float2 ep = make_float2(-e.x, e.y);
            float2 ca = conjf2(va);
            float2 s2 = caddf(vb, ca), d2 = csubf(vb, ca);
            float2 p2 = cmulf(ep, d2);
            float2 Kukp = make_float2(0.5f * (s2.x + p2.y), 0.5f * (s2.y - p2.x));
            pq_pair(Kuk, Kukp, thk, thkp, &Pk, &Qk, &Pkp, &Qkp);
            dst[pqslot(pos)]  = make_float4(Pk.x, Pk.y, Qk.x, Qk.y);     // coalesced: (c<<8)|t
            dst[pqslot(ppos)] = make_float4(Pkp.x, Pkp.y, Qkp.x, Qkp.y); // scattered
        }
    }
}

// ---------------- main convolution: pointwise fused into inverse Q=1 stage ----------------
__global__ void __launch_bounds__(NT, 4) conv16(float* __restrict__ xt,
                                                const float4* __restrict__ PQ,
                                                const float* __restrict__ Dv) {
    __shared__ __align__(16) float2 z[N2];
    int t = threadIdx.x;
    int m = blockIdx.x & (DM - 1);
    int b = blockIdx.x >> 7;
    float2* xrow = (float2*)(xt + (((size_t)b * DM + m) << 12));

    fwd_first(z, xrow, t);  __syncthreads();
    stage_fwd<16>(z, t);    __syncthreads();
    stage_fwd<1>(z, t);     __syncthreads();

    // fused pointwise + inverse Q=1 stage.
    // Read phase: own V + partner V (V stays intact in LDS -> no write hazard yet).
    float2 x[16];
    {
        const float4* pq = PQ + (size_t)m * 4096;
        int j4 = t & 15;
#pragma unroll
        for (int r = 0; r < 16; ++r) {
            int pos = (t << 4) | r;
            float2 va = z[(t << 4) + (r ^ j4)];          // physi(pos)
            int k  = nibrev(pos);
            int kp = (4096 - k) & 4095;
            float2 vb = z[physi(nibrev(kp))];            // partner (self for pos 0,8)
            float4 co = pq[(r << 8) | t];                // coalesced per r
            x[r] = caddf(cmulf(make_float2(co.x, co.y), va),
                         cmulf(make_float2(co.z, co.w), conjf2(vb)));
        }
    }
    __syncthreads();   // all partner reads done before any write below
    {
        float2 Xh[16];
        dft16_inv(x, Xh);
        int j4 = t & 15;
#pragma unroll
        for (int r = 0; r < 16; ++r) {
            int sr = ((r & 3) << 2) | (r >> 2);
            z[(t << 4) + (r ^ j4)] = Xh[sr];
        }
    }
    __syncthreads();

    stage_inv<16>(z, t);    __syncthreads();
    inv_last_store(z, xrow, t, Dv[m]);
}

// ---------------- float4 transposes (R7 verbatim) ----------------
__global__ void transpose_xin(const float* __restrict__ x, float* __restrict__ xt) {
    __shared__ float tile[32][33];
    int b = blockIdx.z;
    int l0 = blockIdx.x * 32, m0 = blockIdx.y * 32;
    int t = threadIdx.x;
    int lr = t >> 3, mc4 = (t & 7) * 4;
    float4 v = *(const float4*)&x[(size_t)b * SEQ * DM + (size_t)(l0 + lr) * DM + m0 + mc4];
    tile[lr][mc4 + 0] = v.x; tile[lr][mc4 + 1] = v.y;
    tile[lr][mc4 + 2] = v.z; tile[lr][mc4 + 3] = v.w;
    __syncthreads();
    int mr = t >> 3, lc4 = (t & 7) * 4;
    float4 o = make_float4(tile[lc4 + 0][mr], tile[lc4 + 1][mr],
                           tile[lc4 + 2][mr], tile[lc4 + 3][mr]);
    *(float4*)&xt[(size_t)b * DM * SEQ + (size_t)(m0 + mr) * SEQ + l0 + lc4] = o;
}

__global__ void transpose_yout(const float* __restrict__ yt, float* __restrict__ out) {
    __shared__ float tile[32][33];
    int b = blockIdx.z;
    int l0 = blockIdx.x * 32, m0 = blockIdx.y * 32;
    int t = threadIdx.x;
    int mr = t >> 3, lc4 = (t & 7) * 4;
    float4 v = *(const float4*)&yt[(size_t)b * DM * SEQ + (size_t)(m0 + mr) * SEQ + l0 + lc4];
    tile[mr][lc4 + 0] = v.x; tile[mr][lc4 + 1] = v.y;
    tile[mr][lc4 + 2] = v.z; tile[mr][lc4 + 3] = v.w;
    __syncthreads();
    int lr = t >> 3, mc4 = (t & 7) * 4;
    float4 o = make_float4(tile[mc4 + 0][lr], tile[mc4 + 1][lr],
                           tile[mc4 + 2][lr], tile[mc4 + 3][lr]);
    *(float4*)&out[(size_t)b * SEQ * DM + (size_t)(l0 + lr) * DM + m0 + mc4] = o;
}

extern "C" void kernel_launch(void* const* d_in, const int* in_sizes, int n_in,
                              void* d_out, int out_size, void* d_ws, size_t ws_size,
                              hipStream_t stream) {
    const float* x     = (const float*)d_in[0];
    const float* Lam   = (const float*)d_in[1];
    const float* Bm    = (const float*)d_in[2];
    const float* Cm    = (const float*)d_in[3];
    const float* Dv    = (const float*)d_in[4];
    const float* logdt = (const float*)d_in[5];
    float* out = (float*)d_out;

    float*  ws   = (float*)d_ws;
    float*  xt   = ws;                                   // 4,194,304 floats (16 MB)
    float4* PQ   = (float4*)(ws + 4194304);              // 128*4096 float4 (8 MB)
    float*  K    = ws + 4194304 + 2097152;               // 524,288 floats (2 MB)
    float*  Psum = K + 524288;                           // 524,288 floats (2 MB)
    float*  GT   = Psum + 524288;                        // 16,384 floats

    hipLaunchKernelGGL(prep_GP,        dim3(320),        dim3(NTP),  0, stream,
                       Lam, logdt, Psum, Cm, Bm, GT);
    hipLaunchKernelGGL(prep_K2,        dim3(256),        dim3(NTP),  0, stream, GT, Psum, K);
    hipLaunchKernelGGL(fftK_PQ,        dim3(128),        dim3(NT),   0, stream, K, PQ);
    hipLaunchKernelGGL(transpose_xin,  dim3(128, 4, 8),  dim3(NT),   0, stream, x, xt);
    hipLaunchKernelGGL(conv16,         dim3(1024),       dim3(NT),   0, stream, xt, PQ, Dv);
    hipLaunchKernelGGL(transpose_yout, dim3(128, 4, 8),  dim3(NT),   0, stream, xt, out);
}